// Round 7
// baseline (383.695 us; speedup 1.0000x reference)
//
#include <hip/hip_runtime.h>
#include <hip/hip_bf16.h>
#include <cmath>

// Problem constants (match reference setup_inputs)
#define NN    50000
#define EE    1600000
#define FIN   512
#define NHEAD 8
#define OUT1  8
#define HID   64      // NHEAD*OUT1
#define NCLS  7

#define NB    391     // ceil(NN/128) buckets of 128 nodes
#define EPB   4096    // edges per block in phase A
#define LOG2E 1.4426950408889634f

// ---------------------------------------------------------------------------
// Workspace layout (4-byte elements):
//   xh      @ 0          N*64   (tmp_r aliases during CSR build)
//   s_j     @ 3,200,000  N*8    (pre-scaled by log2e)
//   sird    @ 3,600,000  N*8 float2  {s_i*log2e, 1/den}
//   dinv    @ 4,400,000  N
//   Binv    @ 4,450,000  N
//   acc_e   @ 4,500,000  N*64   (tmp_c aliases during CSR build)
//   h       @ 7,700,000  N*64
//   xh2     @ 10,900,000 N*8
//   acc_e2  @ 11,300,000 N*8
//   rptr    @ 11,700,000 N+1  int
//   cptr    @ 11,760,000 N+1  int
//   bh_r/bh_c/bs_r/bs_c/bc_r/bc_c @ 11,820,000 + k*1000
//   csr_row_c @ 11,830,000 E  int
//   csr_col_r @ 13,430,000 E  int
// ---------------------------------------------------------------------------
#define OFF_XH     0
#define OFF_SJ     3200000
#define OFF_SIRD   3600000
#define OFF_DINV   4400000
#define OFF_BINV   4450000
#define OFF_ACCE   4500000
#define OFF_H      7700000
#define OFF_XH2    10900000
#define OFF_ACCE2  11300000
#define OFF_RPTR   11700000
#define OFF_CPTR   11760000
#define OFF_BHR    11820000
#define OFF_BHC    11821000
#define OFF_BSR    11822000
#define OFF_BSC    11823000
#define OFF_BCR    11824000
#define OFF_BCC    11825000
#define OFF_CSRRC  11830000
#define OFF_CSRCR  13430000

#define LRELU(a) ((a) > 0.f ? (a) : 0.2f * (a))

__device__ __forceinline__ float fexp2(float x) {
#if __has_builtin(__builtin_amdgcn_exp2f)
  return __builtin_amdgcn_exp2f(x);
#else
  return exp2f(x);
#endif
}

// ---------------------------------------------------------------------------
__global__ __launch_bounds__(512) void zero_small(int* __restrict__ bh_r,
                                                  int* __restrict__ bh_c) {
  int t = threadIdx.x;
  if (t <= NB) { bh_r[t] = 0; bh_c[t] = 0; }
}

// ---------------------------------------------------------------------------
__global__ __launch_bounds__(256) void bucket_hist(const int* __restrict__ ei,
                                                   int* __restrict__ bh_r,
                                                   int* __restrict__ bh_c) {
  __shared__ int hr[NB], hc[NB];
  int t = threadIdx.x;
  for (int i = t; i < NB; i += 256) { hr[i] = 0; hc[i] = 0; }
  __syncthreads();
  for (int i = blockIdx.x * 256 + t; i < EE; i += gridDim.x * 256) {
    atomicAdd(hr + (ei[i] >> 7), 1);
    atomicAdd(hc + (ei[EE + i] >> 7), 1);
  }
  __syncthreads();
  for (int i = t; i < NB; i += 256) {
    if (hr[i]) atomicAdd(bh_r + i, hr[i]);
    if (hc[i]) atomicAdd(bh_c + i, hc[i]);
  }
}

// ---------------------------------------------------------------------------
__global__ __launch_bounds__(512) void bucket_scan(const int* __restrict__ bh_r,
                                                   const int* __restrict__ bh_c,
                                                   int* __restrict__ bs_r,
                                                   int* __restrict__ bs_c,
                                                   int* __restrict__ bc_r,
                                                   int* __restrict__ bc_c) {
  __shared__ int lds[512];
  int t = threadIdx.x;
  for (int side = 0; side < 2; ++side) {
    const int* bh = side ? bh_c : bh_r;
    int* bs = side ? bs_c : bs_r;
    int* bc = side ? bc_c : bc_r;
    int v = (t < NB) ? bh[t] : 0;
    lds[t] = v;
    __syncthreads();
    for (int off = 1; off < 512; off <<= 1) {
      int u = (t >= off) ? lds[t - off] : 0;
      __syncthreads();
      lds[t] += u;
      __syncthreads();
    }
    int excl = lds[t] - v;
    if (t <= NB) bs[t] = excl;
    if (t < NB) bc[t] = excl;
    __syncthreads();
  }
}

// ---------------------------------------------------------------------------
__global__ __launch_bounds__(256) void phaseA(const int* __restrict__ ei,
                                              int* __restrict__ bc_r,
                                              int* __restrict__ bc_c,
                                              int* __restrict__ tmp_r,
                                              int* __restrict__ tmp_c) {
  __shared__ int er[EPB];
  __shared__ int ec[EPB];
  __shared__ int hr[NB], hc[NB];
  const int e0 = blockIdx.x * EPB;
  const int cntE = min(EPB, EE - e0);
  const int t = threadIdx.x;
  for (int i = t; i < cntE; i += 256) { er[i] = ei[e0 + i]; ec[i] = ei[EE + e0 + i]; }
  for (int i = t; i < NB; i += 256) { hr[i] = 0; hc[i] = 0; }
  __syncthreads();
  for (int i = t; i < cntE; i += 256) {
    atomicAdd(hr + (er[i] >> 7), 1);
    atomicAdd(hc + (ec[i] >> 7), 1);
  }
  __syncthreads();
  for (int i = t; i < NB; i += 256) {
    int n = hr[i];
    hr[i] = n ? atomicAdd(bc_r + i, n) : 0;
    n = hc[i];
    hc[i] = n ? atomicAdd(bc_c + i, n) : 0;
  }
  __syncthreads();
  for (int i = t; i < cntE; i += 256) {
    int r = er[i], c = ec[i];
    int pr = atomicAdd(hr + (r >> 7), 1);
    tmp_r[pr] = ((r & 127) << 16) | c;
    int pc = atomicAdd(hc + (c >> 7), 1);
    tmp_c[pc] = ((c & 127) << 16) | r;
  }
}

// ---------------------------------------------------------------------------
__global__ __launch_bounds__(256) void phaseB(const int* __restrict__ tmp_r,
                                              const int* __restrict__ tmp_c,
                                              const int* __restrict__ bs_r,
                                              const int* __restrict__ bs_c,
                                              const float* __restrict__ hw,
                                              int* __restrict__ rptr,
                                              int* __restrict__ cptr,
                                              int* __restrict__ csr_row_c,
                                              int* __restrict__ csr_col_r,
                                              float* __restrict__ Binv) {
  const int side = blockIdx.x >= NB ? 1 : 0;
  const int b = blockIdx.x - side * NB;
  const int* tmp = side ? tmp_c : tmp_r;
  const int* bs = side ? bs_c : bs_r;
  int* ptr = side ? cptr : rptr;
  int* csr = side ? csr_col_r : csr_row_c;

  const int base = bs[b];
  const int M = bs[b + 1] - base;
  __shared__ int cnt[128], pre[128], cur[128];
  const int t = threadIdx.x;
  if (t < 128) cnt[t] = 0;
  __syncthreads();
  for (int i = t; i < M; i += 256) atomicAdd(cnt + (tmp[base + i] >> 16), 1);
  __syncthreads();
  if (t < 128) pre[t] = cnt[t];
  __syncthreads();
  for (int off = 1; off < 128; off <<= 1) {
    int u = (t >= off && t < 128) ? pre[t - off] : 0;
    __syncthreads();
    if (t < 128) pre[t] += u;
    __syncthreads();
  }
  const int node0 = b << 7;
  if (t < 128) {
    int excl = pre[t] - cnt[t];
    int g = node0 + t;
    if (g <= NN) ptr[g] = base + excl;
    cur[t] = base + excl;
    if (side && g < NN) Binv[g] = cnt[t] > 0 ? hw[g] / (float)cnt[t] : 0.f;
  }
  __syncthreads();
  for (int i = t; i < M; i += 256) {
    int e = tmp[base + i];
    int pos = atomicAdd(cur + (e >> 16), 1);
    csr[pos] = e & 0xFFFF;
  }
}

// ---------------------------------------------------------------------------
// GEMM1: xh[N,64] = x[N,512] @ W1[512,64].  64x64 tile, BK=32, 4x4 microtile.
// Double-buffered LDS + register prefetch (1 barrier / k-tile).
// Staging: waves 0-1 load x (lane=row, 64B/lane, transposed LDS write is
// 2-way-bank = free); waves 2-3 load W.
__global__ __launch_bounds__(256) void gemm1_kernel(const float* __restrict__ x,
                                                    const float* __restrict__ W1,
                                                    float* __restrict__ xh) {
  __shared__ float lx[2][32][68];  // [buf][k][row]
  __shared__ float lw[2][32][68];  // [buf][k][col]
  const int t = threadIdx.x;
  const int row0 = blockIdx.x * 64;
  const int ty = t >> 4, tx = t & 15;
  const int r0 = ty * 4, c0 = tx * 4;
  const bool isX = t < 128;
  const int srow = t & 63;              // x-stage: row within tile
  const int sk = (t >> 6) * 16;         // x-stage: k-offset (waves 0,1 -> 0,16)
  const int wu = t - 128;               // W-stage thread index
  const int wk = wu >> 2;               // W-stage: k row (0..31)
  const int wc = (wu & 3) * 16;         // W-stage: col offset

  float4 p0, p1, p2, p3;  // prefetch regs (x halves or W quarters)

#define G1_PREFETCH(kb)                                                      \
  {                                                                          \
    if (isX) {                                                               \
      int grow = row0 + srow;                                                \
      if (grow < NN) {                                                       \
        const float4* p = reinterpret_cast<const float4*>(                   \
            x + (size_t)grow * FIN + (kb) + sk);                             \
        p0 = p[0]; p1 = p[1]; p2 = p[2]; p3 = p[3];                          \
      } else {                                                               \
        p0 = make_float4(0.f, 0.f, 0.f, 0.f); p1 = p0; p2 = p0; p3 = p0;     \
      }                                                                      \
    } else {                                                                 \
      const float4* q = reinterpret_cast<const float4*>(                     \
          W1 + (size_t)((kb) + wk) * HID + wc);                              \
      p0 = q[0]; p1 = q[1]; p2 = q[2]; p3 = q[3];                            \
    }                                                                        \
  }

#define G1_COMMIT(buf)                                                       \
  {                                                                          \
    if (isX) {                                                               \
      float v[16] = {p0.x, p0.y, p0.z, p0.w, p1.x, p1.y, p1.z, p1.w,         \
                     p2.x, p2.y, p2.z, p2.w, p3.x, p3.y, p3.z, p3.w};        \
      _Pragma("unroll")                                                      \
      for (int i = 0; i < 16; ++i) lx[buf][sk + i][srow] = v[i];             \
    } else {                                                                 \
      *reinterpret_cast<float4*>(&lw[buf][wk][wc + 0])  = p0;                \
      *reinterpret_cast<float4*>(&lw[buf][wk][wc + 4])  = p1;                \
      *reinterpret_cast<float4*>(&lw[buf][wk][wc + 8])  = p2;                \
      *reinterpret_cast<float4*>(&lw[buf][wk][wc + 12]) = p3;                \
    }                                                                        \
  }

  float acc[4][4] = {};
  G1_PREFETCH(0);
  G1_COMMIT(0);
  __syncthreads();

  for (int tt = 0; tt < FIN / 32; ++tt) {
    const int cur = tt & 1;
    if (tt < FIN / 32 - 1) G1_PREFETCH((tt + 1) * 32);
#pragma unroll
    for (int kk = 0; kk < 32; ++kk) {
      const float4 af = *reinterpret_cast<const float4*>(&lx[cur][kk][r0]);
      const float4 bf = *reinterpret_cast<const float4*>(&lw[cur][kk][c0]);
      const float a4[4] = {af.x, af.y, af.z, af.w};
      const float b4[4] = {bf.x, bf.y, bf.z, bf.w};
#pragma unroll
      for (int i = 0; i < 4; ++i)
#pragma unroll
        for (int j = 0; j < 4; ++j)
          acc[i][j] = fmaf(a4[i], b4[j], acc[i][j]);
    }
    if (tt < FIN / 32 - 1) G1_COMMIT(cur ^ 1);
    __syncthreads();
  }
#undef G1_PREFETCH
#undef G1_COMMIT

#pragma unroll
  for (int i = 0; i < 4; ++i) {
    int gr = row0 + r0 + i;
    if (gr < NN) {
      float4 v = make_float4(acc[i][0], acc[i][1], acc[i][2], acc[i][3]);
      *reinterpret_cast<float4*>(xh + (size_t)gr * HID + c0) = v;
    }
  }
}

// ---------------------------------------------------------------------------
// Attention projections, PRE-SCALED by log2e so all exps become exp2.
__global__ __launch_bounds__(256) void attscore_kernel(const float* __restrict__ xh,
                                                       const float* __restrict__ att1,
                                                       float2* __restrict__ sird,
                                                       float* __restrict__ s_j) {
  int t = blockIdx.x * 256 + threadIdx.x;
  if (t >= NN * NHEAD) return;
  int n = t >> 3, hh = t & 7;
  const float* xp = xh + (size_t)n * HID + hh * OUT1;
  float si = 0.f, sj = 0.f;
#pragma unroll
  for (int c = 0; c < OUT1; ++c) {
    float v = xp[c];
    si = fmaf(v, att1[hh * 16 + c], si);
    sj = fmaf(v, att1[hh * 16 + 8 + c], sj);
  }
  sird[t] = make_float2(si * LOG2E, 0.f);
  s_j[t] = sj * LOG2E;
}

// ---------------------------------------------------------------------------
// Softmax denominator (reciprocal -> sird.y) + node degree (Dinv) per row.
__global__ __launch_bounds__(256) void den_csr(const int* __restrict__ rptr,
                                               const int* __restrict__ csr_row_c,
                                               const float* __restrict__ s_j,
                                               const float* __restrict__ hw,
                                               float2* __restrict__ sird,
                                               float* __restrict__ dinv) {
  int wid = (blockIdx.x * 256 + threadIdx.x) >> 6;
  int lane = threadIdx.x & 63;
  if (wid >= NN) return;
  int r = wid;
  int hh = lane & 7;
  int eslot = lane >> 3;
  float si = sird[r * 8 + hh].x;
  int beg = rptr[r], end = rptr[r + 1];
  float aexp = 0.f, ad = 0.f;
  int i = beg + eslot;
  for (; i + 8 < end; i += 16) {
    int c0 = csr_row_c[i], c1 = csr_row_c[i + 8];
    float sj0 = s_j[c0 * 8 + hh], sj1 = s_j[c1 * 8 + hh];
    float h0 = hw[c0], h1 = hw[c1];
    float a0 = LRELU(si + sj0), a1 = LRELU(si + sj1);
    aexp += fexp2(a0) + fexp2(a1);
    ad += h0 + h1;
  }
  if (i < end) {
    int c = csr_row_c[i];
    float a = LRELU(si + s_j[c * 8 + hh]);
    aexp += fexp2(a);
    ad += hw[c];
  }
  aexp += __shfl_xor(aexp, 8);
  aexp += __shfl_xor(aexp, 16);
  aexp += __shfl_xor(aexp, 32);
  ad += __shfl_xor(ad, 8);
  ad += __shfl_xor(ad, 16);
  ad += __shfl_xor(ad, 32);
  if (eslot == 0) {
    reinterpret_cast<float*>(sird)[(r * 8 + hh) * 2 + 1] = 1.0f / (aexp + 1e-16f);
    if (hh == 0) dinv[r] = ad > 0.f ? 1.0f / ad : 0.f;
  }
}

// ---------------------------------------------------------------------------
// Propagate 1 (nodes -> hyperedges): wave per hyperedge c, lane = channel.
// 8-edge batches: lane (hh*8+j) computes alpha(edge j, head hh) ONCE, then
// shuffles distribute r (uniform idx) and alpha (per-lane idx) for the fmas.
__global__ __launch_bounds__(256) void prop1_csr(const int* __restrict__ cptr,
                                                 const int* __restrict__ csr_col_r,
                                                 const float* __restrict__ xh,
                                                 const float2* __restrict__ sird,
                                                 const float* __restrict__ s_j,
                                                 const float* __restrict__ Binv,
                                                 float* __restrict__ acc_e) {
  int wid = (blockIdx.x * 256 + threadIdx.x) >> 6;
  int lane = threadIdx.x & 63;
  if (wid >= NN) return;
  const int c = wid;
  const int hh = lane >> 3;
  const int j = lane & 7;
  const int abase = lane & 56;  // hh*8: shfl source base for my head's alphas
  float sj = s_j[c * 8 + hh];
  int beg = cptr[c], end = cptr[c + 1];
  float acc = 0.f;
  int i = beg;
  for (; i + 8 <= end; i += 8) {
    int rj = csr_col_r[i + j];
    float2 q = sird[rj * 8 + hh];
    float a = LRELU(q.x + sj);
    float aexp = fexp2(a) * q.y;  // alpha(edge j, head hh)
#pragma unroll
    for (int j2 = 0; j2 < 8; ++j2) {
      int r = __shfl(rj, j2);
      float al = __shfl(aexp, abase + j2);
      acc = fmaf(xh[(r << 6) + lane], al, acc);
    }
  }
  for (; i < end; ++i) {
    int r = csr_col_r[i];
    float2 q = sird[r * 8 + hh];
    float a = LRELU(q.x + sj);
    acc = fmaf(xh[(r << 6) + lane], fexp2(a) * q.y, acc);
  }
  acc_e[(c << 6) + lane] = acc * Binv[c];
}

// ---------------------------------------------------------------------------
// Propagate 2 (hyperedges -> nodes) + finish1: wave per node r, same batching.
__global__ __launch_bounds__(256) void prop2_csr(const int* __restrict__ rptr,
                                                 const int* __restrict__ csr_row_c,
                                                 const float* __restrict__ acc_e,
                                                 const float2* __restrict__ sird,
                                                 const float* __restrict__ s_j,
                                                 const float* __restrict__ dinv,
                                                 const float* __restrict__ b1,
                                                 float* __restrict__ h) {
  int wid = (blockIdx.x * 256 + threadIdx.x) >> 6;
  int lane = threadIdx.x & 63;
  if (wid >= NN) return;
  const int r = wid;
  const int hh = lane >> 3;
  const int j = lane & 7;
  const int abase = lane & 56;
  float2 sr = sird[r * 8 + hh];
  const float si = sr.x, rd = sr.y;
  int beg = rptr[r], end = rptr[r + 1];
  float acc = 0.f;
  int i = beg;
  for (; i + 8 <= end; i += 8) {
    int cj = csr_row_c[i + j];
    float sjv = s_j[cj * 8 + hh];
    float aexp = fexp2(LRELU(si + sjv));  // exp(a) for (edge j, head hh)
#pragma unroll
    for (int j2 = 0; j2 < 8; ++j2) {
      int cc = __shfl(cj, j2);
      float al = __shfl(aexp, abase + j2);
      acc = fmaf(acc_e[(cc << 6) + lane], al, acc);
    }
  }
  for (; i < end; ++i) {
    int cc = csr_row_c[i];
    float aexp = fexp2(LRELU(si + s_j[cc * 8 + hh]));
    acc = fmaf(acc_e[(cc << 6) + lane], aexp, acc);
  }
  acc *= rd;  // softmax reciprocal factored out of the loop
  float v = fmaf(acc, dinv[r], b1[lane]);
  h[(r << 6) + lane] = v > 0.f ? v : expm1f(v);
}

// ---------------------------------------------------------------------------
// GEMM2: xh2[n,k] = sum_c h[n,c]*W2[c,k]  (k<7; slot 7 zeroed)
__global__ __launch_bounds__(256) void gemm2_kernel(const float* __restrict__ h,
                                                    const float* __restrict__ W2,
                                                    float* __restrict__ xh2) {
  int t = blockIdx.x * 256 + threadIdx.x;
  if (t >= NN * 8) return;
  int n = t >> 3, k = t & 7;
  if (k == 7) { xh2[t] = 0.f; return; }
  const float* hp = h + (size_t)n * HID;
  float acc = 0.f;
#pragma unroll
  for (int c = 0; c < HID; ++c) acc = fmaf(hp[c], W2[c * NCLS + k], acc);
  xh2[t] = acc;
}

// ---------------------------------------------------------------------------
// Layer-2 propagate 1: acc_e2[g] = Binv[g] * sum_r xh2[r]
__global__ __launch_bounds__(256) void prop3_csr(const int* __restrict__ cptr,
                                                 const int* __restrict__ csr_col_r,
                                                 const float* __restrict__ xh2,
                                                 const float* __restrict__ Binv,
                                                 float* __restrict__ acc_e2) {
  int t = blockIdx.x * 256 + threadIdx.x;
  int g = t >> 3, k = t & 7;
  if (g >= NN) return;
  int beg = cptr[g], end = cptr[g + 1];
  float acc = 0.f;
  int i = beg;
  for (; i + 3 < end; i += 4) {
    int r0 = csr_col_r[i], r1 = csr_col_r[i + 1];
    int r2 = csr_col_r[i + 2], r3 = csr_col_r[i + 3];
    float v0 = xh2[r0 * 8 + k], v1 = xh2[r1 * 8 + k];
    float v2 = xh2[r2 * 8 + k], v3 = xh2[r3 * 8 + k];
    acc += (v0 + v1) + (v2 + v3);
  }
  for (; i < end; ++i) acc += xh2[csr_col_r[i] * 8 + k];
  acc_e2[g * 8 + k] = acc * Binv[g];
}

// ---------------------------------------------------------------------------
// Layer-2 propagate 2 + log_softmax: 8 lanes per node.
__global__ __launch_bounds__(256) void prop4_csr(const int* __restrict__ rptr,
                                                 const int* __restrict__ csr_row_c,
                                                 const float* __restrict__ acc_e2,
                                                 const float* __restrict__ dinv,
                                                 const float* __restrict__ b2,
                                                 float* __restrict__ out) {
  int t = blockIdx.x * 256 + threadIdx.x;
  int r = t >> 3, k = t & 7;
  if (r >= NN) return;
  int beg = rptr[r], end = rptr[r + 1];
  float acc = 0.f;
  int i = beg;
  for (; i + 3 < end; i += 4) {
    int c0 = csr_row_c[i], c1 = csr_row_c[i + 1];
    int c2 = csr_row_c[i + 2], c3 = csr_row_c[i + 3];
    float v0 = acc_e2[c0 * 8 + k], v1 = acc_e2[c1 * 8 + k];
    float v2 = acc_e2[c2 * 8 + k], v3 = acc_e2[c3 * 8 + k];
    acc += (v0 + v1) + (v2 + v3);
  }
  for (; i < end; ++i) acc += acc_e2[csr_row_c[i] * 8 + k];
  float v = (k < NCLS) ? fmaf(acc, dinv[r], b2[k]) : -INFINITY;
  float m = v;
  m = fmaxf(m, __shfl_xor(m, 1, 8));
  m = fmaxf(m, __shfl_xor(m, 2, 8));
  m = fmaxf(m, __shfl_xor(m, 4, 8));
  float ex = (k < NCLS) ? expf(v - m) : 0.f;
  float s = ex;
  s += __shfl_xor(s, 1, 8);
  s += __shfl_xor(s, 2, 8);
  s += __shfl_xor(s, 4, 8);
  float lse = m + logf(s);
  if (k < NCLS) out[(size_t)r * NCLS + k] = v - lse;
}

// ---------------------------------------------------------------------------
extern "C" void kernel_launch(void* const* d_in, const int* in_sizes, int n_in,
                              void* d_out, int out_size, void* d_ws, size_t ws_size,
                              hipStream_t stream) {
  const float* x    = (const float*)d_in[0];
  const int*   ei   = (const int*)d_in[1];
  const float* hw   = (const float*)d_in[2];
  const float* W1   = (const float*)d_in[3];
  const float* att1 = (const float*)d_in[4];
  const float* b1   = (const float*)d_in[5];
  const float* W2   = (const float*)d_in[6];
  const float* b2   = (const float*)d_in[7];
  float* out = (float*)d_out;
  float* ws  = (float*)d_ws;

  float* xh     = ws + OFF_XH;
  float* s_j    = ws + OFF_SJ;
  float2* sird  = (float2*)(ws + OFF_SIRD);
  float* dinv   = ws + OFF_DINV;
  float* Binv   = ws + OFF_BINV;
  float* acc_e  = ws + OFF_ACCE;
  float* hbuf   = ws + OFF_H;
  float* xh2    = ws + OFF_XH2;
  float* acc_e2 = ws + OFF_ACCE2;
  int* rptr = (int*)(ws + OFF_RPTR);
  int* cptr = (int*)(ws + OFF_CPTR);
  int* bh_r = (int*)(ws + OFF_BHR);
  int* bh_c = (int*)(ws + OFF_BHC);
  int* bs_r = (int*)(ws + OFF_BSR);
  int* bs_c = (int*)(ws + OFF_BSC);
  int* bc_r = (int*)(ws + OFF_BCR);
  int* bc_c = (int*)(ws + OFF_BCC);
  int* csr_row_c = (int*)(ws + OFF_CSRRC);
  int* csr_col_r = (int*)(ws + OFF_CSRCR);
  int* tmp_r = (int*)(ws + OFF_XH);    // aliases xh (consumed before xh written)
  int* tmp_c = (int*)(ws + OFF_ACCE);  // aliases acc_e

  // --- CSR build (bucketed counting sort, both orderings) ---
  zero_small<<<1, 512, 0, stream>>>(bh_r, bh_c);
  bucket_hist<<<256, 256, 0, stream>>>(ei, bh_r, bh_c);
  bucket_scan<<<1, 512, 0, stream>>>(bh_r, bh_c, bs_r, bs_c, bc_r, bc_c);
  phaseA<<<(EE + EPB - 1) / EPB, 256, 0, stream>>>(ei, bc_r, bc_c, tmp_r, tmp_c);
  phaseB<<<2 * NB, 256, 0, stream>>>(tmp_r, tmp_c, bs_r, bs_c, hw,
                                     rptr, cptr, csr_row_c, csr_col_r, Binv);

  // --- Layer 1 ---
  gemm1_kernel<<<(NN + 63) / 64, 256, 0, stream>>>(x, W1, xh);
  attscore_kernel<<<(NN * NHEAD + 255) / 256, 256, 0, stream>>>(xh, att1, sird, s_j);
  den_csr<<<(NN * 64 + 255) / 256, 256, 0, stream>>>(rptr, csr_row_c, s_j, hw, sird, dinv);
  prop1_csr<<<(NN * 64 + 255) / 256, 256, 0, stream>>>(cptr, csr_col_r, xh, sird, s_j, Binv, acc_e);
  prop2_csr<<<(NN * 64 + 255) / 256, 256, 0, stream>>>(rptr, csr_row_c, acc_e, sird, s_j,
                                                       dinv, b1, hbuf);

  // --- Layer 2 ---
  gemm2_kernel<<<(NN * 8 + 255) / 256, 256, 0, stream>>>(hbuf, W2, xh2);
  prop3_csr<<<(NN * 8 + 255) / 256, 256, 0, stream>>>(cptr, csr_col_r, xh2, Binv, acc_e2);
  prop4_csr<<<(NN * 8 + 255) / 256, 256, 0, stream>>>(rptr, csr_row_c, acc_e2, dinv, b2, out);
}

// Round 8
// 363.270 us; speedup vs baseline: 1.0562x; 1.0562x over previous
//
#include <hip/hip_runtime.h>
#include <hip/hip_bf16.h>
#include <cmath>

// Problem constants (match reference setup_inputs)
#define NN    50000
#define EE    1600000
#define FIN   512
#define NHEAD 8
#define OUT1  8
#define HID   64      // NHEAD*OUT1
#define NCLS  7

#define NB    391     // ceil(NN/128) buckets of 128 nodes
#define EPB   4096    // edges per block in phase A
#define LOG2E 1.4426950408889634f

// ---------------------------------------------------------------------------
// Workspace layout (4-byte elements):
//   xh      @ 0          N*64   (tmp_r aliases during CSR build)
//   s_j     @ 3,200,000  N*8    (pre-scaled by log2e)
//   sird    @ 3,600,000  N*8 float2  {s_i*log2e, 1/den}
//   dinv    @ 4,400,000  N
//   Binv    @ 4,450,000  N
//   acc_e   @ 4,500,000  N*64   (tmp_c aliases during CSR build)
//   h       @ 7,700,000  N*64
//   xh2     @ 10,900,000 N*8
//   acc_e2  @ 11,300,000 N*8
//   rptr    @ 11,700,000 N+1  int
//   cptr    @ 11,760,000 N+1  int
//   bh_r/bh_c/bs_r/bs_c/bc_r/bc_c @ 11,820,000 + k*1000
//   csr_row_c @ 11,830,000 E  int
//   csr_col_r @ 13,430,000 E  int
// ---------------------------------------------------------------------------
#define OFF_XH     0
#define OFF_SJ     3200000
#define OFF_SIRD   3600000
#define OFF_DINV   4400000
#define OFF_BINV   4450000
#define OFF_ACCE   4500000
#define OFF_H      7700000
#define OFF_XH2    10900000
#define OFF_ACCE2  11300000
#define OFF_RPTR   11700000
#define OFF_CPTR   11760000
#define OFF_BHR    11820000
#define OFF_BHC    11821000
#define OFF_BSR    11822000
#define OFF_BSC    11823000
#define OFF_BCR    11824000
#define OFF_BCC    11825000
#define OFF_CSRRC  11830000
#define OFF_CSRCR  13430000

#define LRELU(a) ((a) > 0.f ? (a) : 0.2f * (a))

__device__ __forceinline__ float fexp2(float x) {
#if __has_builtin(__builtin_amdgcn_exp2f)
  return __builtin_amdgcn_exp2f(x);
#else
  return exp2f(x);
#endif
}

// ---------------------------------------------------------------------------
__global__ __launch_bounds__(512) void zero_small(int* __restrict__ bh_r,
                                                  int* __restrict__ bh_c) {
  int t = threadIdx.x;
  if (t <= NB) { bh_r[t] = 0; bh_c[t] = 0; }
}

// ---------------------------------------------------------------------------
__global__ __launch_bounds__(256) void bucket_hist(const int* __restrict__ ei,
                                                   int* __restrict__ bh_r,
                                                   int* __restrict__ bh_c) {
  __shared__ int hr[NB], hc[NB];
  int t = threadIdx.x;
  for (int i = t; i < NB; i += 256) { hr[i] = 0; hc[i] = 0; }
  __syncthreads();
  for (int i = blockIdx.x * 256 + t; i < EE; i += gridDim.x * 256) {
    atomicAdd(hr + (ei[i] >> 7), 1);
    atomicAdd(hc + (ei[EE + i] >> 7), 1);
  }
  __syncthreads();
  for (int i = t; i < NB; i += 256) {
    if (hr[i]) atomicAdd(bh_r + i, hr[i]);
    if (hc[i]) atomicAdd(bh_c + i, hc[i]);
  }
}

// ---------------------------------------------------------------------------
__global__ __launch_bounds__(512) void bucket_scan(const int* __restrict__ bh_r,
                                                   const int* __restrict__ bh_c,
                                                   int* __restrict__ bs_r,
                                                   int* __restrict__ bs_c,
                                                   int* __restrict__ bc_r,
                                                   int* __restrict__ bc_c) {
  __shared__ int lds[512];
  int t = threadIdx.x;
  for (int side = 0; side < 2; ++side) {
    const int* bh = side ? bh_c : bh_r;
    int* bs = side ? bs_c : bs_r;
    int* bc = side ? bc_c : bc_r;
    int v = (t < NB) ? bh[t] : 0;
    lds[t] = v;
    __syncthreads();
    for (int off = 1; off < 512; off <<= 1) {
      int u = (t >= off) ? lds[t - off] : 0;
      __syncthreads();
      lds[t] += u;
      __syncthreads();
    }
    int excl = lds[t] - v;
    if (t <= NB) bs[t] = excl;
    if (t < NB) bc[t] = excl;
    __syncthreads();
  }
}

// ---------------------------------------------------------------------------
__global__ __launch_bounds__(256) void phaseA(const int* __restrict__ ei,
                                              int* __restrict__ bc_r,
                                              int* __restrict__ bc_c,
                                              int* __restrict__ tmp_r,
                                              int* __restrict__ tmp_c) {
  __shared__ int er[EPB];
  __shared__ int ec[EPB];
  __shared__ int hr[NB], hc[NB];
  const int e0 = blockIdx.x * EPB;
  const int cntE = min(EPB, EE - e0);
  const int t = threadIdx.x;
  for (int i = t; i < cntE; i += 256) { er[i] = ei[e0 + i]; ec[i] = ei[EE + e0 + i]; }
  for (int i = t; i < NB; i += 256) { hr[i] = 0; hc[i] = 0; }
  __syncthreads();
  for (int i = t; i < cntE; i += 256) {
    atomicAdd(hr + (er[i] >> 7), 1);
    atomicAdd(hc + (ec[i] >> 7), 1);
  }
  __syncthreads();
  for (int i = t; i < NB; i += 256) {
    int n = hr[i];
    hr[i] = n ? atomicAdd(bc_r + i, n) : 0;
    n = hc[i];
    hc[i] = n ? atomicAdd(bc_c + i, n) : 0;
  }
  __syncthreads();
  for (int i = t; i < cntE; i += 256) {
    int r = er[i], c = ec[i];
    int pr = atomicAdd(hr + (r >> 7), 1);
    tmp_r[pr] = ((r & 127) << 16) | c;
    int pc = atomicAdd(hc + (c >> 7), 1);
    tmp_c[pc] = ((c & 127) << 16) | r;
  }
}

// ---------------------------------------------------------------------------
__global__ __launch_bounds__(256) void phaseB(const int* __restrict__ tmp_r,
                                              const int* __restrict__ tmp_c,
                                              const int* __restrict__ bs_r,
                                              const int* __restrict__ bs_c,
                                              const float* __restrict__ hw,
                                              int* __restrict__ rptr,
                                              int* __restrict__ cptr,
                                              int* __restrict__ csr_row_c,
                                              int* __restrict__ csr_col_r,
                                              float* __restrict__ Binv) {
  const int side = blockIdx.x >= NB ? 1 : 0;
  const int b = blockIdx.x - side * NB;
  const int* tmp = side ? tmp_c : tmp_r;
  const int* bs = side ? bs_c : bs_r;
  int* ptr = side ? cptr : rptr;
  int* csr = side ? csr_col_r : csr_row_c;

  const int base = bs[b];
  const int M = bs[b + 1] - base;
  __shared__ int cnt[128], pre[128], cur[128];
  const int t = threadIdx.x;
  if (t < 128) cnt[t] = 0;
  __syncthreads();
  for (int i = t; i < M; i += 256) atomicAdd(cnt + (tmp[base + i] >> 16), 1);
  __syncthreads();
  if (t < 128) pre[t] = cnt[t];
  __syncthreads();
  for (int off = 1; off < 128; off <<= 1) {
    int u = (t >= off && t < 128) ? pre[t - off] : 0;
    __syncthreads();
    if (t < 128) pre[t] += u;
    __syncthreads();
  }
  const int node0 = b << 7;
  if (t < 128) {
    int excl = pre[t] - cnt[t];
    int g = node0 + t;
    if (g <= NN) ptr[g] = base + excl;
    cur[t] = base + excl;
    if (side && g < NN) Binv[g] = cnt[t] > 0 ? hw[g] / (float)cnt[t] : 0.f;
  }
  __syncthreads();
  for (int i = t; i < M; i += 256) {
    int e = tmp[base + i];
    int pos = atomicAdd(cur + (e >> 16), 1);
    csr[pos] = e & 0xFFFF;
  }
}

// ---------------------------------------------------------------------------
// GEMM1: xh[N,64] = x[N,512] @ W1[512,64].  32x64 tile, BK=32, 2x4 microtile,
// 256 threads, single-buffered (compiler schedules), conflict-free staging.
// Grid = 1563 blocks -> ~6 blocks/CU (fixes round-6's grid-limited occupancy).
__global__ __launch_bounds__(256) void gemm1_kernel(const float* __restrict__ x,
                                                    const float* __restrict__ W1,
                                                    float* __restrict__ xh) {
  __shared__ float lx[32][34];  // [k][row]  (34 pad -> 2-way bank on writes)
  __shared__ float lw[32][68];  // [k][col]
  const int t = threadIdx.x;
  const int row0 = blockIdx.x * 32;
  const int ty = t >> 4, tx = t & 15;
  const int r0 = ty * 2, c0 = tx * 4;
  // x-stage mapping: row = t>>3 (0..31), k-offset = (t&7)*4
  const int sr = t >> 3;
  const int sk = (t & 7) * 4;
  // W-stage mapping: k-row = t>>3, col-offset = (t&7)*8
  const int wk = t >> 3;
  const int wc = (t & 7) * 8;
  const int grow = row0 + sr;

  float acc[2][4] = {};

  for (int kb = 0; kb < FIN; kb += 32) {
    // stage x (transposed): one float4 per thread
    {
      float4 a0 = make_float4(0.f, 0.f, 0.f, 0.f);
      if (grow < NN)
        a0 = *reinterpret_cast<const float4*>(x + (size_t)grow * FIN + kb + sk);
      lx[sk + 0][sr] = a0.x;
      lx[sk + 1][sr] = a0.y;
      lx[sk + 2][sr] = a0.z;
      lx[sk + 3][sr] = a0.w;
    }
    // stage W: two float4 per thread
    {
      const float4* q = reinterpret_cast<const float4*>(W1 + (size_t)(kb + wk) * HID + wc);
      float4 b0 = q[0], b1v = q[1];
      *reinterpret_cast<float4*>(&lw[wk][wc]) = b0;
      *reinterpret_cast<float4*>(&lw[wk][wc + 4]) = b1v;
    }
    __syncthreads();
#pragma unroll
    for (int kk = 0; kk < 32; ++kk) {
      const float2 af = *reinterpret_cast<const float2*>(&lx[kk][r0]);
      const float4 bf = *reinterpret_cast<const float4*>(&lw[kk][c0]);
      const float a2[2] = {af.x, af.y};
      const float b4[4] = {bf.x, bf.y, bf.z, bf.w};
#pragma unroll
      for (int i = 0; i < 2; ++i)
#pragma unroll
        for (int j = 0; j < 4; ++j)
          acc[i][j] = fmaf(a2[i], b4[j], acc[i][j]);
    }
    __syncthreads();
  }
#pragma unroll
  for (int i = 0; i < 2; ++i) {
    int gr = row0 + r0 + i;
    if (gr < NN) {
      float4 v = make_float4(acc[i][0], acc[i][1], acc[i][2], acc[i][3]);
      *reinterpret_cast<float4*>(xh + (size_t)gr * HID + c0) = v;
    }
  }
}

// ---------------------------------------------------------------------------
// Attention projections, PRE-SCALED by log2e so all exps become exp2.
__global__ __launch_bounds__(256) void attscore_kernel(const float* __restrict__ xh,
                                                       const float* __restrict__ att1,
                                                       float2* __restrict__ sird,
                                                       float* __restrict__ s_j) {
  int t = blockIdx.x * 256 + threadIdx.x;
  if (t >= NN * NHEAD) return;
  int n = t >> 3, hh = t & 7;
  const float* xp = xh + (size_t)n * HID + hh * OUT1;
  float si = 0.f, sj = 0.f;
#pragma unroll
  for (int c = 0; c < OUT1; ++c) {
    float v = xp[c];
    si = fmaf(v, att1[hh * 16 + c], si);
    sj = fmaf(v, att1[hh * 16 + 8 + c], sj);
  }
  sird[t] = make_float2(si * LOG2E, 0.f);
  s_j[t] = sj * LOG2E;
}

// ---------------------------------------------------------------------------
// Softmax denominator (reciprocal -> sird.y) + node degree (Dinv) per row.
__global__ __launch_bounds__(256) void den_csr(const int* __restrict__ rptr,
                                               const int* __restrict__ csr_row_c,
                                               const float* __restrict__ s_j,
                                               const float* __restrict__ hw,
                                               float2* __restrict__ sird,
                                               float* __restrict__ dinv) {
  int wid = (blockIdx.x * 256 + threadIdx.x) >> 6;
  int lane = threadIdx.x & 63;
  if (wid >= NN) return;
  int r = wid;
  int hh = lane & 7;
  int eslot = lane >> 3;
  float si = sird[r * 8 + hh].x;
  int beg = rptr[r], end = rptr[r + 1];
  float aexp = 0.f, ad = 0.f;
  int i = beg + eslot;
  for (; i + 8 < end; i += 16) {
    int c0 = csr_row_c[i], c1 = csr_row_c[i + 8];
    float sj0 = s_j[c0 * 8 + hh], sj1 = s_j[c1 * 8 + hh];
    float h0 = hw[c0], h1 = hw[c1];
    float a0 = LRELU(si + sj0), a1 = LRELU(si + sj1);
    aexp += fexp2(a0) + fexp2(a1);
    ad += h0 + h1;
  }
  if (i < end) {
    int c = csr_row_c[i];
    float a = LRELU(si + s_j[c * 8 + hh]);
    aexp += fexp2(a);
    ad += hw[c];
  }
  aexp += __shfl_xor(aexp, 8);
  aexp += __shfl_xor(aexp, 16);
  aexp += __shfl_xor(aexp, 32);
  ad += __shfl_xor(ad, 8);
  ad += __shfl_xor(ad, 16);
  ad += __shfl_xor(ad, 32);
  if (eslot == 0) {
    reinterpret_cast<float*>(sird)[(r * 8 + hh) * 2 + 1] = 1.0f / (aexp + 1e-16f);
    if (hh == 0) dinv[r] = ad > 0.f ? 1.0f / ad : 0.f;
  }
}

// ---------------------------------------------------------------------------
// Propagate 1 (nodes -> hyperedges): wave per hyperedge c, lane = channel.
// 8-edge batches: lane (hh*8+j) computes alpha(edge j, head hh) ONCE, then
// shuffles distribute r (uniform idx) and alpha (per-lane idx) for the fmas.
__global__ __launch_bounds__(256) void prop1_csr(const int* __restrict__ cptr,
                                                 const int* __restrict__ csr_col_r,
                                                 const float* __restrict__ xh,
                                                 const float2* __restrict__ sird,
                                                 const float* __restrict__ s_j,
                                                 const float* __restrict__ Binv,
                                                 float* __restrict__ acc_e) {
  int wid = (blockIdx.x * 256 + threadIdx.x) >> 6;
  int lane = threadIdx.x & 63;
  if (wid >= NN) return;
  const int c = wid;
  const int hh = lane >> 3;
  const int j = lane & 7;
  const int abase = lane & 56;  // hh*8: shfl source base for my head's alphas
  float sj = s_j[c * 8 + hh];
  int beg = cptr[c], end = cptr[c + 1];
  float acc = 0.f;
  int i = beg;
  for (; i + 8 <= end; i += 8) {
    int rj = csr_col_r[i + j];
    float2 q = sird[rj * 8 + hh];
    float a = LRELU(q.x + sj);
    float aexp = fexp2(a) * q.y;  // alpha(edge j, head hh)
#pragma unroll
    for (int j2 = 0; j2 < 8; ++j2) {
      int r = __shfl(rj, j2);
      float al = __shfl(aexp, abase + j2);
      acc = fmaf(xh[(r << 6) + lane], al, acc);
    }
  }
  for (; i < end; ++i) {
    int r = csr_col_r[i];
    float2 q = sird[r * 8 + hh];
    float a = LRELU(q.x + sj);
    acc = fmaf(xh[(r << 6) + lane], fexp2(a) * q.y, acc);
  }
  acc_e[(c << 6) + lane] = acc * Binv[c];
}

// ---------------------------------------------------------------------------
// Propagate 2 (hyperedges -> nodes) + finish1: wave per node r, same batching.
__global__ __launch_bounds__(256) void prop2_csr(const int* __restrict__ rptr,
                                                 const int* __restrict__ csr_row_c,
                                                 const float* __restrict__ acc_e,
                                                 const float2* __restrict__ sird,
                                                 const float* __restrict__ s_j,
                                                 const float* __restrict__ dinv,
                                                 const float* __restrict__ b1,
                                                 float* __restrict__ h) {
  int wid = (blockIdx.x * 256 + threadIdx.x) >> 6;
  int lane = threadIdx.x & 63;
  if (wid >= NN) return;
  const int r = wid;
  const int hh = lane >> 3;
  const int j = lane & 7;
  const int abase = lane & 56;
  float2 sr = sird[r * 8 + hh];
  const float si = sr.x, rd = sr.y;
  int beg = rptr[r], end = rptr[r + 1];
  float acc = 0.f;
  int i = beg;
  for (; i + 8 <= end; i += 8) {
    int cj = csr_row_c[i + j];
    float sjv = s_j[cj * 8 + hh];
    float aexp = fexp2(LRELU(si + sjv));  // exp(a) for (edge j, head hh)
#pragma unroll
    for (int j2 = 0; j2 < 8; ++j2) {
      int cc = __shfl(cj, j2);
      float al = __shfl(aexp, abase + j2);
      acc = fmaf(acc_e[(cc << 6) + lane], al, acc);
    }
  }
  for (; i < end; ++i) {
    int cc = csr_row_c[i];
    float aexp = fexp2(LRELU(si + s_j[cc * 8 + hh]));
    acc = fmaf(acc_e[(cc << 6) + lane], aexp, acc);
  }
  acc *= rd;  // softmax reciprocal factored out of the loop
  float v = fmaf(acc, dinv[r], b1[lane]);
  h[(r << 6) + lane] = v > 0.f ? v : expm1f(v);
}

// ---------------------------------------------------------------------------
// GEMM2: xh2[n,k] = sum_c h[n,c]*W2[c,k]  (k<7; slot 7 zeroed)
__global__ __launch_bounds__(256) void gemm2_kernel(const float* __restrict__ h,
                                                    const float* __restrict__ W2,
                                                    float* __restrict__ xh2) {
  int t = blockIdx.x * 256 + threadIdx.x;
  if (t >= NN * 8) return;
  int n = t >> 3, k = t & 7;
  if (k == 7) { xh2[t] = 0.f; return; }
  const float* hp = h + (size_t)n * HID;
  float acc = 0.f;
#pragma unroll
  for (int c = 0; c < HID; ++c) acc = fmaf(hp[c], W2[c * NCLS + k], acc);
  xh2[t] = acc;
}

// ---------------------------------------------------------------------------
// Layer-2 propagate 1: acc_e2[g] = Binv[g] * sum_r xh2[r]
__global__ __launch_bounds__(256) void prop3_csr(const int* __restrict__ cptr,
                                                 const int* __restrict__ csr_col_r,
                                                 const float* __restrict__ xh2,
                                                 const float* __restrict__ Binv,
                                                 float* __restrict__ acc_e2) {
  int t = blockIdx.x * 256 + threadIdx.x;
  int g = t >> 3, k = t & 7;
  if (g >= NN) return;
  int beg = cptr[g], end = cptr[g + 1];
  float acc = 0.f;
  int i = beg;
  for (; i + 3 < end; i += 4) {
    int r0 = csr_col_r[i], r1 = csr_col_r[i + 1];
    int r2 = csr_col_r[i + 2], r3 = csr_col_r[i + 3];
    float v0 = xh2[r0 * 8 + k], v1 = xh2[r1 * 8 + k];
    float v2 = xh2[r2 * 8 + k], v3 = xh2[r3 * 8 + k];
    acc += (v0 + v1) + (v2 + v3);
  }
  for (; i < end; ++i) acc += xh2[csr_col_r[i] * 8 + k];
  acc_e2[g * 8 + k] = acc * Binv[g];
}

// ---------------------------------------------------------------------------
// Layer-2 propagate 2 + log_softmax: 8 lanes per node.
__global__ __launch_bounds__(256) void prop4_csr(const int* __restrict__ rptr,
                                                 const int* __restrict__ csr_row_c,
                                                 const float* __restrict__ acc_e2,
                                                 const float* __restrict__ dinv,
                                                 const float* __restrict__ b2,
                                                 float* __restrict__ out) {
  int t = blockIdx.x * 256 + threadIdx.x;
  int r = t >> 3, k = t & 7;
  if (r >= NN) return;
  int beg = rptr[r], end = rptr[r + 1];
  float acc = 0.f;
  int i = beg;
  for (; i + 3 < end; i += 4) {
    int c0 = csr_row_c[i], c1 = csr_row_c[i + 1];
    int c2 = csr_row_c[i + 2], c3 = csr_row_c[i + 3];
    float v0 = acc_e2[c0 * 8 + k], v1 = acc_e2[c1 * 8 + k];
    float v2 = acc_e2[c2 * 8 + k], v3 = acc_e2[c3 * 8 + k];
    acc += (v0 + v1) + (v2 + v3);
  }
  for (; i < end; ++i) acc += acc_e2[csr_row_c[i] * 8 + k];
  float v = (k < NCLS) ? fmaf(acc, dinv[r], b2[k]) : -INFINITY;
  float m = v;
  m = fmaxf(m, __shfl_xor(m, 1, 8));
  m = fmaxf(m, __shfl_xor(m, 2, 8));
  m = fmaxf(m, __shfl_xor(m, 4, 8));
  float ex = (k < NCLS) ? expf(v - m) : 0.f;
  float s = ex;
  s += __shfl_xor(s, 1, 8);
  s += __shfl_xor(s, 2, 8);
  s += __shfl_xor(s, 4, 8);
  float lse = m + logf(s);
  if (k < NCLS) out[(size_t)r * NCLS + k] = v - lse;
}

// ---------------------------------------------------------------------------
extern "C" void kernel_launch(void* const* d_in, const int* in_sizes, int n_in,
                              void* d_out, int out_size, void* d_ws, size_t ws_size,
                              hipStream_t stream) {
  const float* x    = (const float*)d_in[0];
  const int*   ei   = (const int*)d_in[1];
  const float* hw   = (const float*)d_in[2];
  const float* W1   = (const float*)d_in[3];
  const float* att1 = (const float*)d_in[4];
  const float* b1   = (const float*)d_in[5];
  const float* W2   = (const float*)d_in[6];
  const float* b2   = (const float*)d_in[7];
  float* out = (float*)d_out;
  float* ws  = (float*)d_ws;

  float* xh     = ws + OFF_XH;
  float* s_j    = ws + OFF_SJ;
  float2* sird  = (float2*)(ws + OFF_SIRD);
  float* dinv   = ws + OFF_DINV;
  float* Binv   = ws + OFF_BINV;
  float* acc_e  = ws + OFF_ACCE;
  float* hbuf   = ws + OFF_H;
  float* xh2    = ws + OFF_XH2;
  float* acc_e2 = ws + OFF_ACCE2;
  int* rptr = (int*)(ws + OFF_RPTR);
  int* cptr = (int*)(ws + OFF_CPTR);
  int* bh_r = (int*)(ws + OFF_BHR);
  int* bh_c = (int*)(ws + OFF_BHC);
  int* bs_r = (int*)(ws + OFF_BSR);
  int* bs_c = (int*)(ws + OFF_BSC);
  int* bc_r = (int*)(ws + OFF_BCR);
  int* bc_c = (int*)(ws + OFF_BCC);
  int* csr_row_c = (int*)(ws + OFF_CSRRC);
  int* csr_col_r = (int*)(ws + OFF_CSRCR);
  int* tmp_r = (int*)(ws + OFF_XH);    // aliases xh (consumed before xh written)
  int* tmp_c = (int*)(ws + OFF_ACCE);  // aliases acc_e

  // --- CSR build (bucketed counting sort, both orderings) ---
  zero_small<<<1, 512, 0, stream>>>(bh_r, bh_c);
  bucket_hist<<<256, 256, 0, stream>>>(ei, bh_r, bh_c);
  bucket_scan<<<1, 512, 0, stream>>>(bh_r, bh_c, bs_r, bs_c, bc_r, bc_c);
  phaseA<<<(EE + EPB - 1) / EPB, 256, 0, stream>>>(ei, bc_r, bc_c, tmp_r, tmp_c);
  phaseB<<<2 * NB, 256, 0, stream>>>(tmp_r, tmp_c, bs_r, bs_c, hw,
                                     rptr, cptr, csr_row_c, csr_col_r, Binv);

  // --- Layer 1 ---
  gemm1_kernel<<<(NN + 31) / 32, 256, 0, stream>>>(x, W1, xh);
  attscore_kernel<<<(NN * NHEAD + 255) / 256, 256, 0, stream>>>(xh, att1, sird, s_j);
  den_csr<<<(NN * 64 + 255) / 256, 256, 0, stream>>>(rptr, csr_row_c, s_j, hw, sird, dinv);
  prop1_csr<<<(NN * 64 + 255) / 256, 256, 0, stream>>>(cptr, csr_col_r, xh, sird, s_j, Binv, acc_e);
  prop2_csr<<<(NN * 64 + 255) / 256, 256, 0, stream>>>(rptr, csr_row_c, acc_e, sird, s_j,
                                                       dinv, b1, hbuf);

  // --- Layer 2 ---
  gemm2_kernel<<<(NN * 8 + 255) / 256, 256, 0, stream>>>(hbuf, W2, xh2);
  prop3_csr<<<(NN * 8 + 255) / 256, 256, 0, stream>>>(cptr, csr_col_r, xh2, Binv, acc_e2);
  prop4_csr<<<(NN * 8 + 255) / 256, 256, 0, stream>>>(rptr, csr_row_c, acc_e2, dinv, b2, out);
}

// Round 9
// 348.466 us; speedup vs baseline: 1.1011x; 1.0425x over previous
//
#include <hip/hip_runtime.h>
#include <hip/hip_bf16.h>
#include <cmath>

// Problem constants (match reference setup_inputs)
#define NN    50000
#define EE    1600000
#define FIN   512
#define NHEAD 8
#define OUT1  8
#define HID   64      // NHEAD*OUT1
#define NCLS  7

#define NB    391     // ceil(NN/128) buckets of 128 nodes
#define EPB   4096    // edges per block in phase A
#define LOG2E 1.4426950408889634f

// ---------------------------------------------------------------------------
// Workspace layout (4-byte elements):
//   xh      @ 0          N*64   (tmp_r aliases during CSR build; gemm1 partial p0)
//   s_j     @ 3,200,000  N*8    (pre-scaled by log2e)
//   sird    @ 3,600,000  N*8 float2  {s_i*log2e, 1/den}
//   dinv    @ 4,400,000  N
//   Binv    @ 4,450,000  N
//   acc_e   @ 4,500,000  N*64   (tmp_c aliases during CSR build)
//   h       @ 7,700,000  N*64   (gemm1 partial p1 before prop2 writes h)
//   xh2     @ 10,900,000 N*8
//   acc_e2  @ 11,300,000 N*8
//   rptr    @ 11,700,000 N+1  int
//   cptr    @ 11,760,000 N+1  int
//   bh_r/bh_c/bs_r/bs_c/bc_r/bc_c @ 11,820,000 + k*1000
//   csr_row_c @ 11,830,000 E  int
//   csr_col_r @ 13,430,000 E  int
// ---------------------------------------------------------------------------
#define OFF_XH     0
#define OFF_SJ     3200000
#define OFF_SIRD   3600000
#define OFF_DINV   4400000
#define OFF_BINV   4450000
#define OFF_ACCE   4500000
#define OFF_H      7700000
#define OFF_XH2    10900000
#define OFF_ACCE2  11300000
#define OFF_RPTR   11700000
#define OFF_CPTR   11760000
#define OFF_BHR    11820000
#define OFF_BHC    11821000
#define OFF_BSR    11822000
#define OFF_BSC    11823000
#define OFF_BCR    11824000
#define OFF_BCC    11825000
#define OFF_CSRRC  11830000
#define OFF_CSRCR  13430000

#define LRELU(a) ((a) > 0.f ? (a) : 0.2f * (a))

__device__ __forceinline__ float fexp2(float x) {
#if __has_builtin(__builtin_amdgcn_exp2f)
  return __builtin_amdgcn_exp2f(x);
#else
  return exp2f(x);
#endif
}

// ---------------------------------------------------------------------------
__global__ __launch_bounds__(512) void zero_small(int* __restrict__ bh_r,
                                                  int* __restrict__ bh_c) {
  int t = threadIdx.x;
  if (t <= NB) { bh_r[t] = 0; bh_c[t] = 0; }
}

// ---------------------------------------------------------------------------
__global__ __launch_bounds__(256) void bucket_hist(const int* __restrict__ ei,
                                                   int* __restrict__ bh_r,
                                                   int* __restrict__ bh_c) {
  __shared__ int hr[NB], hc[NB];
  int t = threadIdx.x;
  for (int i = t; i < NB; i += 256) { hr[i] = 0; hc[i] = 0; }
  __syncthreads();
  for (int i = blockIdx.x * 256 + t; i < EE; i += gridDim.x * 256) {
    atomicAdd(hr + (ei[i] >> 7), 1);
    atomicAdd(hc + (ei[EE + i] >> 7), 1);
  }
  __syncthreads();
  for (int i = t; i < NB; i += 256) {
    if (hr[i]) atomicAdd(bh_r + i, hr[i]);
    if (hc[i]) atomicAdd(bh_c + i, hc[i]);
  }
}

// ---------------------------------------------------------------------------
__global__ __launch_bounds__(512) void bucket_scan(const int* __restrict__ bh_r,
                                                   const int* __restrict__ bh_c,
                                                   int* __restrict__ bs_r,
                                                   int* __restrict__ bs_c,
                                                   int* __restrict__ bc_r,
                                                   int* __restrict__ bc_c) {
  __shared__ int lds[512];
  int t = threadIdx.x;
  for (int side = 0; side < 2; ++side) {
    const int* bh = side ? bh_c : bh_r;
    int* bs = side ? bs_c : bs_r;
    int* bc = side ? bc_c : bc_r;
    int v = (t < NB) ? bh[t] : 0;
    lds[t] = v;
    __syncthreads();
    for (int off = 1; off < 512; off <<= 1) {
      int u = (t >= off) ? lds[t - off] : 0;
      __syncthreads();
      lds[t] += u;
      __syncthreads();
    }
    int excl = lds[t] - v;
    if (t <= NB) bs[t] = excl;
    if (t < NB) bc[t] = excl;
    __syncthreads();
  }
}

// ---------------------------------------------------------------------------
__global__ __launch_bounds__(256) void phaseA(const int* __restrict__ ei,
                                              int* __restrict__ bc_r,
                                              int* __restrict__ bc_c,
                                              int* __restrict__ tmp_r,
                                              int* __restrict__ tmp_c) {
  __shared__ int er[EPB];
  __shared__ int ec[EPB];
  __shared__ int hr[NB], hc[NB];
  const int e0 = blockIdx.x * EPB;
  const int cntE = min(EPB, EE - e0);
  const int t = threadIdx.x;
  for (int i = t; i < cntE; i += 256) { er[i] = ei[e0 + i]; ec[i] = ei[EE + e0 + i]; }
  for (int i = t; i < NB; i += 256) { hr[i] = 0; hc[i] = 0; }
  __syncthreads();
  for (int i = t; i < cntE; i += 256) {
    atomicAdd(hr + (er[i] >> 7), 1);
    atomicAdd(hc + (ec[i] >> 7), 1);
  }
  __syncthreads();
  for (int i = t; i < NB; i += 256) {
    int n = hr[i];
    hr[i] = n ? atomicAdd(bc_r + i, n) : 0;
    n = hc[i];
    hc[i] = n ? atomicAdd(bc_c + i, n) : 0;
  }
  __syncthreads();
  for (int i = t; i < cntE; i += 256) {
    int r = er[i], c = ec[i];
    int pr = atomicAdd(hr + (r >> 7), 1);
    tmp_r[pr] = ((r & 127) << 16) | c;
    int pc = atomicAdd(hc + (c >> 7), 1);
    tmp_c[pc] = ((c & 127) << 16) | r;
  }
}

// ---------------------------------------------------------------------------
__global__ __launch_bounds__(256) void phaseB(const int* __restrict__ tmp_r,
                                              const int* __restrict__ tmp_c,
                                              const int* __restrict__ bs_r,
                                              const int* __restrict__ bs_c,
                                              const float* __restrict__ hw,
                                              int* __restrict__ rptr,
                                              int* __restrict__ cptr,
                                              int* __restrict__ csr_row_c,
                                              int* __restrict__ csr_col_r,
                                              float* __restrict__ Binv) {
  const int side = blockIdx.x >= NB ? 1 : 0;
  const int b = blockIdx.x - side * NB;
  const int* tmp = side ? tmp_c : tmp_r;
  const int* bs = side ? bs_c : bs_r;
  int* ptr = side ? cptr : rptr;
  int* csr = side ? csr_col_r : csr_row_c;

  const int base = bs[b];
  const int M = bs[b + 1] - base;
  __shared__ int cnt[128], pre[128], cur[128];
  const int t = threadIdx.x;
  if (t < 128) cnt[t] = 0;
  __syncthreads();
  for (int i = t; i < M; i += 256) atomicAdd(cnt + (tmp[base + i] >> 16), 1);
  __syncthreads();
  if (t < 128) pre[t] = cnt[t];
  __syncthreads();
  for (int off = 1; off < 128; off <<= 1) {
    int u = (t >= off && t < 128) ? pre[t - off] : 0;
    __syncthreads();
    if (t < 128) pre[t] += u;
    __syncthreads();
  }
  const int node0 = b << 7;
  if (t < 128) {
    int excl = pre[t] - cnt[t];
    int g = node0 + t;
    if (g <= NN) ptr[g] = base + excl;
    cur[t] = base + excl;
    if (side && g < NN) Binv[g] = cnt[t] > 0 ? hw[g] / (float)cnt[t] : 0.f;
  }
  __syncthreads();
  for (int i = t; i < M; i += 256) {
    int e = tmp[base + i];
    int pos = atomicAdd(cur + (e >> 16), 1);
    csr[pos] = e & 0xFFFF;
  }
}

// ---------------------------------------------------------------------------
// GEMM1 split-K: blockIdx.y selects K-half [0,256) / [256,512) and the output
// partial buffer.  64x64 tile, BK=32, 4x4 microtile, conflict-free staging.
// Grid = 782 x 2 = 1564 blocks -> ~24 waves/CU (vs 12 for full-K).
__global__ __launch_bounds__(256) void gemm1_kernel(const float* __restrict__ x,
                                                    const float* __restrict__ W1,
                                                    float* __restrict__ p0,
                                                    float* __restrict__ p1) {
  __shared__ float lx[32][66];  // [k][row]; 66 pad -> 2-way banks (free)
  __shared__ float lw[32][68];  // [k][col]
  const int t = threadIdx.x;
  const int row0 = blockIdx.x * 64;
  const int kbase = blockIdx.y * (FIN / 2);
  float* __restrict__ dst = blockIdx.y ? p1 : p0;
  const int ty = t >> 4, tx = t & 15;
  const int r0 = ty * 4, c0 = tx * 4;
  // x-stage: row = t>>2 (0..63), k-offset = (t&3)*8 ; two float4 per thread
  const int sr = t >> 2;
  const int sk = (t & 3) * 8;
  const int grow = row0 + sr;
  // W-stage: k-row = t>>3 (0..31), col-offset = (t&7)*8 ; two float4 per thread
  const int wk = t >> 3;
  const int wc = (t & 7) * 8;

  float acc[4][4] = {};

  for (int kb = kbase; kb < kbase + FIN / 2; kb += 32) {
    // stage x (transposed)
    {
      float4 a0 = make_float4(0.f, 0.f, 0.f, 0.f), a1 = a0;
      if (grow < NN) {
        const float4* p = reinterpret_cast<const float4*>(x + (size_t)grow * FIN + kb + sk);
        a0 = p[0]; a1 = p[1];
      }
      lx[sk + 0][sr] = a0.x; lx[sk + 1][sr] = a0.y;
      lx[sk + 2][sr] = a0.z; lx[sk + 3][sr] = a0.w;
      lx[sk + 4][sr] = a1.x; lx[sk + 5][sr] = a1.y;
      lx[sk + 6][sr] = a1.z; lx[sk + 7][sr] = a1.w;
    }
    // stage W
    {
      const float4* q = reinterpret_cast<const float4*>(W1 + (size_t)(kb + wk) * HID + wc);
      float4 b0 = q[0], b1v = q[1];
      *reinterpret_cast<float4*>(&lw[wk][wc]) = b0;
      *reinterpret_cast<float4*>(&lw[wk][wc + 4]) = b1v;
    }
    __syncthreads();
#pragma unroll
    for (int kk = 0; kk < 32; ++kk) {
      const float4 af = *reinterpret_cast<const float4*>(&lx[kk][r0]);
      const float4 bf = *reinterpret_cast<const float4*>(&lw[kk][c0]);
      const float a4[4] = {af.x, af.y, af.z, af.w};
      const float b4[4] = {bf.x, bf.y, bf.z, bf.w};
#pragma unroll
      for (int i = 0; i < 4; ++i)
#pragma unroll
        for (int j = 0; j < 4; ++j)
          acc[i][j] = fmaf(a4[i], b4[j], acc[i][j]);
    }
    __syncthreads();
  }
#pragma unroll
  for (int i = 0; i < 4; ++i) {
    int gr = row0 + r0 + i;
    if (gr < NN) {
      float4 v = make_float4(acc[i][0], acc[i][1], acc[i][2], acc[i][3]);
      *reinterpret_cast<float4*>(dst + (size_t)gr * HID + c0) = v;
    }
  }
}

// ---------------------------------------------------------------------------
// Attention projections + split-K reduction: xh = p0 + p1 (written in-place
// into p0 == xh region), sird.x = s_i*log2e, s_j = s_j*log2e.
__global__ __launch_bounds__(256) void attscore_kernel(float* __restrict__ xh,   // p0, summed in-place
                                                       const float* __restrict__ p1,
                                                       const float* __restrict__ att1,
                                                       float2* __restrict__ sird,
                                                       float* __restrict__ s_j) {
  int t = blockIdx.x * 256 + threadIdx.x;
  if (t >= NN * NHEAD) return;
  int hh = t & 7;
  const size_t base = (size_t)t * 8;   // == n*64 + hh*8
  float4 a0 = *reinterpret_cast<const float4*>(xh + base);
  float4 a1 = *reinterpret_cast<const float4*>(xh + base + 4);
  float4 q0 = *reinterpret_cast<const float4*>(p1 + base);
  float4 q1 = *reinterpret_cast<const float4*>(p1 + base + 4);
  float v[8] = {a0.x + q0.x, a0.y + q0.y, a0.z + q0.z, a0.w + q0.w,
                a1.x + q1.x, a1.y + q1.y, a1.z + q1.z, a1.w + q1.w};
  float si = 0.f, sj = 0.f;
#pragma unroll
  for (int c = 0; c < OUT1; ++c) {
    si = fmaf(v[c], att1[hh * 16 + c], si);
    sj = fmaf(v[c], att1[hh * 16 + 8 + c], sj);
  }
  *reinterpret_cast<float4*>(xh + base)     = make_float4(v[0], v[1], v[2], v[3]);
  *reinterpret_cast<float4*>(xh + base + 4) = make_float4(v[4], v[5], v[6], v[7]);
  sird[t] = make_float2(si * LOG2E, 0.f);
  s_j[t] = sj * LOG2E;
}

// ---------------------------------------------------------------------------
// Softmax denominator (reciprocal -> sird.y) + node degree (Dinv) per row.
__global__ __launch_bounds__(256) void den_csr(const int* __restrict__ rptr,
                                               const int* __restrict__ csr_row_c,
                                               const float* __restrict__ s_j,
                                               const float* __restrict__ hw,
                                               float2* __restrict__ sird,
                                               float* __restrict__ dinv) {
  int wid = (blockIdx.x * 256 + threadIdx.x) >> 6;
  int lane = threadIdx.x & 63;
  if (wid >= NN) return;
  int r = wid;
  int hh = lane & 7;
  int eslot = lane >> 3;
  float si = sird[r * 8 + hh].x;
  int beg = rptr[r], end = rptr[r + 1];
  float aexp = 0.f, ad = 0.f;
  int i = beg + eslot;
  for (; i + 8 < end; i += 16) {
    int c0 = csr_row_c[i], c1 = csr_row_c[i + 8];
    float sj0 = s_j[c0 * 8 + hh], sj1 = s_j[c1 * 8 + hh];
    float h0 = hw[c0], h1 = hw[c1];
    float a0 = LRELU(si + sj0), a1 = LRELU(si + sj1);
    aexp += fexp2(a0) + fexp2(a1);
    ad += h0 + h1;
  }
  if (i < end) {
    int c = csr_row_c[i];
    float a = LRELU(si + s_j[c * 8 + hh]);
    aexp += fexp2(a);
    ad += hw[c];
  }
  aexp += __shfl_xor(aexp, 8);
  aexp += __shfl_xor(aexp, 16);
  aexp += __shfl_xor(aexp, 32);
  ad += __shfl_xor(ad, 8);
  ad += __shfl_xor(ad, 16);
  ad += __shfl_xor(ad, 32);
  if (eslot == 0) {
    reinterpret_cast<float*>(sird)[(r * 8 + hh) * 2 + 1] = 1.0f / (aexp + 1e-16f);
    if (hh == 0) dinv[r] = ad > 0.f ? 1.0f / ad : 0.f;
  }
}

// ---------------------------------------------------------------------------
// Propagate 1 (nodes -> hyperedges): wave per hyperedge c, lane = channel.
// 8-edge batches: lane (hh*8+j) computes alpha(edge j, head hh) ONCE, then
// shuffles distribute r (uniform idx) and alpha (per-lane idx) for the fmas.
__global__ __launch_bounds__(256) void prop1_csr(const int* __restrict__ cptr,
                                                 const int* __restrict__ csr_col_r,
                                                 const float* __restrict__ xh,
                                                 const float2* __restrict__ sird,
                                                 const float* __restrict__ s_j,
                                                 const float* __restrict__ Binv,
                                                 float* __restrict__ acc_e) {
  int wid = (blockIdx.x * 256 + threadIdx.x) >> 6;
  int lane = threadIdx.x & 63;
  if (wid >= NN) return;
  const int c = wid;
  const int hh = lane >> 3;
  const int j = lane & 7;
  const int abase = lane & 56;  // hh*8: shfl source base for my head's alphas
  float sj = s_j[c * 8 + hh];
  int beg = cptr[c], end = cptr[c + 1];
  float acc = 0.f;
  int i = beg;
  for (; i + 8 <= end; i += 8) {
    int rj = csr_col_r[i + j];
    float2 q = sird[rj * 8 + hh];
    float a = LRELU(q.x + sj);
    float aexp = fexp2(a) * q.y;  // alpha(edge j, head hh)
#pragma unroll
    for (int j2 = 0; j2 < 8; ++j2) {
      int r = __shfl(rj, j2);
      float al = __shfl(aexp, abase + j2);
      acc = fmaf(xh[(r << 6) + lane], al, acc);
    }
  }
  for (; i < end; ++i) {
    int r = csr_col_r[i];
    float2 q = sird[r * 8 + hh];
    float a = LRELU(q.x + sj);
    acc = fmaf(xh[(r << 6) + lane], fexp2(a) * q.y, acc);
  }
  acc_e[(c << 6) + lane] = acc * Binv[c];
}

// ---------------------------------------------------------------------------
// Propagate 2 (hyperedges -> nodes) + finish1: wave per node r, same batching.
__global__ __launch_bounds__(256) void prop2_csr(const int* __restrict__ rptr,
                                                 const int* __restrict__ csr_row_c,
                                                 const float* __restrict__ acc_e,
                                                 const float2* __restrict__ sird,
                                                 const float* __restrict__ s_j,
                                                 const float* __restrict__ dinv,
                                                 const float* __restrict__ b1,
                                                 float* __restrict__ h) {
  int wid = (blockIdx.x * 256 + threadIdx.x) >> 6;
  int lane = threadIdx.x & 63;
  if (wid >= NN) return;
  const int r = wid;
  const int hh = lane >> 3;
  const int j = lane & 7;
  const int abase = lane & 56;
  float2 sr = sird[r * 8 + hh];
  const float si = sr.x, rd = sr.y;
  int beg = rptr[r], end = rptr[r + 1];
  float acc = 0.f;
  int i = beg;
  for (; i + 8 <= end; i += 8) {
    int cj = csr_row_c[i + j];
    float sjv = s_j[cj * 8 + hh];
    float aexp = fexp2(LRELU(si + sjv));  // exp(a) for (edge j, head hh)
#pragma unroll
    for (int j2 = 0; j2 < 8; ++j2) {
      int cc = __shfl(cj, j2);
      float al = __shfl(aexp, abase + j2);
      acc = fmaf(acc_e[(cc << 6) + lane], al, acc);
    }
  }
  for (; i < end; ++i) {
    int cc = csr_row_c[i];
    float aexp = fexp2(LRELU(si + s_j[cc * 8 + hh]));
    acc = fmaf(acc_e[(cc << 6) + lane], aexp, acc);
  }
  acc *= rd;  // softmax reciprocal factored out of the loop
  float v = fmaf(acc, dinv[r], b1[lane]);
  h[(r << 6) + lane] = v > 0.f ? v : expm1f(v);
}

// ---------------------------------------------------------------------------
// GEMM2: xh2[n,k] = sum_c h[n,c]*W2[c,k]  (k<7; slot 7 zeroed)
__global__ __launch_bounds__(256) void gemm2_kernel(const float* __restrict__ h,
                                                    const float* __restrict__ W2,
                                                    float* __restrict__ xh2) {
  int t = blockIdx.x * 256 + threadIdx.x;
  if (t >= NN * 8) return;
  int n = t >> 3, k = t & 7;
  if (k == 7) { xh2[t] = 0.f; return; }
  const float* hp = h + (size_t)n * HID;
  float acc = 0.f;
#pragma unroll
  for (int c = 0; c < HID; ++c) acc = fmaf(hp[c], W2[c * NCLS + k], acc);
  xh2[t] = acc;
}

// ---------------------------------------------------------------------------
// Layer-2 propagate 1: acc_e2[g] = Binv[g] * sum_r xh2[r]
__global__ __launch_bounds__(256) void prop3_csr(const int* __restrict__ cptr,
                                                 const int* __restrict__ csr_col_r,
                                                 const float* __restrict__ xh2,
                                                 const float* __restrict__ Binv,
                                                 float* __restrict__ acc_e2) {
  int t = blockIdx.x * 256 + threadIdx.x;
  int g = t >> 3, k = t & 7;
  if (g >= NN) return;
  int beg = cptr[g], end = cptr[g + 1];
  float acc = 0.f;
  int i = beg;
  for (; i + 3 < end; i += 4) {
    int r0 = csr_col_r[i], r1 = csr_col_r[i + 1];
    int r2 = csr_col_r[i + 2], r3 = csr_col_r[i + 3];
    float v0 = xh2[r0 * 8 + k], v1 = xh2[r1 * 8 + k];
    float v2 = xh2[r2 * 8 + k], v3 = xh2[r3 * 8 + k];
    acc += (v0 + v1) + (v2 + v3);
  }
  for (; i < end; ++i) acc += xh2[csr_col_r[i] * 8 + k];
  acc_e2[g * 8 + k] = acc * Binv[g];
}

// ---------------------------------------------------------------------------
// Layer-2 propagate 2 + log_softmax: 8 lanes per node.
__global__ __launch_bounds__(256) void prop4_csr(const int* __restrict__ rptr,
                                                 const int* __restrict__ csr_row_c,
                                                 const float* __restrict__ acc_e2,
                                                 const float* __restrict__ dinv,
                                                 const float* __restrict__ b2,
                                                 float* __restrict__ out) {
  int t = blockIdx.x * 256 + threadIdx.x;
  int r = t >> 3, k = t & 7;
  if (r >= NN) return;
  int beg = rptr[r], end = rptr[r + 1];
  float acc = 0.f;
  int i = beg;
  for (; i + 3 < end; i += 4) {
    int c0 = csr_row_c[i], c1 = csr_row_c[i + 1];
    int c2 = csr_row_c[i + 2], c3 = csr_row_c[i + 3];
    float v0 = acc_e2[c0 * 8 + k], v1 = acc_e2[c1 * 8 + k];
    float v2 = acc_e2[c2 * 8 + k], v3 = acc_e2[c3 * 8 + k];
    acc += (v0 + v1) + (v2 + v3);
  }
  for (; i < end; ++i) acc += acc_e2[csr_row_c[i] * 8 + k];
  float v = (k < NCLS) ? fmaf(acc, dinv[r], b2[k]) : -INFINITY;
  float m = v;
  m = fmaxf(m, __shfl_xor(m, 1, 8));
  m = fmaxf(m, __shfl_xor(m, 2, 8));
  m = fmaxf(m, __shfl_xor(m, 4, 8));
  float ex = (k < NCLS) ? expf(v - m) : 0.f;
  float s = ex;
  s += __shfl_xor(s, 1, 8);
  s += __shfl_xor(s, 2, 8);
  s += __shfl_xor(s, 4, 8);
  float lse = m + logf(s);
  if (k < NCLS) out[(size_t)r * NCLS + k] = v - lse;
}

// ---------------------------------------------------------------------------
extern "C" void kernel_launch(void* const* d_in, const int* in_sizes, int n_in,
                              void* d_out, int out_size, void* d_ws, size_t ws_size,
                              hipStream_t stream) {
  const float* x    = (const float*)d_in[0];
  const int*   ei   = (const int*)d_in[1];
  const float* hw   = (const float*)d_in[2];
  const float* W1   = (const float*)d_in[3];
  const float* att1 = (const float*)d_in[4];
  const float* b1   = (const float*)d_in[5];
  const float* W2   = (const float*)d_in[6];
  const float* b2   = (const float*)d_in[7];
  float* out = (float*)d_out;
  float* ws  = (float*)d_ws;

  float* xh     = ws + OFF_XH;     // gemm1 partial p0, then xh = p0+p1
  float* s_j    = ws + OFF_SJ;
  float2* sird  = (float2*)(ws + OFF_SIRD);
  float* dinv   = ws + OFF_DINV;
  float* Binv   = ws + OFF_BINV;
  float* acc_e  = ws + OFF_ACCE;
  float* hbuf   = ws + OFF_H;      // gemm1 partial p1, then h (prop2 output)
  float* xh2    = ws + OFF_XH2;
  float* acc_e2 = ws + OFF_ACCE2;
  int* rptr = (int*)(ws + OFF_RPTR);
  int* cptr = (int*)(ws + OFF_CPTR);
  int* bh_r = (int*)(ws + OFF_BHR);
  int* bh_c = (int*)(ws + OFF_BHC);
  int* bs_r = (int*)(ws + OFF_BSR);
  int* bs_c = (int*)(ws + OFF_BSC);
  int* bc_r = (int*)(ws + OFF_BCR);
  int* bc_c = (int*)(ws + OFF_BCC);
  int* csr_row_c = (int*)(ws + OFF_CSRRC);
  int* csr_col_r = (int*)(ws + OFF_CSRCR);
  int* tmp_r = (int*)(ws + OFF_XH);    // aliases xh (consumed before gemm1 writes)
  int* tmp_c = (int*)(ws + OFF_ACCE);  // aliases acc_e

  // --- CSR build (bucketed counting sort, both orderings) ---
  zero_small<<<1, 512, 0, stream>>>(bh_r, bh_c);
  bucket_hist<<<256, 256, 0, stream>>>(ei, bh_r, bh_c);
  bucket_scan<<<1, 512, 0, stream>>>(bh_r, bh_c, bs_r, bs_c, bc_r, bc_c);
  phaseA<<<(EE + EPB - 1) / EPB, 256, 0, stream>>>(ei, bc_r, bc_c, tmp_r, tmp_c);
  phaseB<<<2 * NB, 256, 0, stream>>>(tmp_r, tmp_c, bs_r, bs_c, hw,
                                     rptr, cptr, csr_row_c, csr_col_r, Binv);

  // --- Layer 1 ---
  {
    dim3 g((NN + 63) / 64, 2);
    gemm1_kernel<<<g, 256, 0, stream>>>(x, W1, xh, hbuf);
  }
  attscore_kernel<<<(NN * NHEAD + 255) / 256, 256, 0, stream>>>(xh, hbuf, att1, sird, s_j);
  den_csr<<<(NN * 64 + 255) / 256, 256, 0, stream>>>(rptr, csr_row_c, s_j, hw, sird, dinv);
  prop1_csr<<<(NN * 64 + 255) / 256, 256, 0, stream>>>(cptr, csr_col_r, xh, sird, s_j, Binv, acc_e);
  prop2_csr<<<(NN * 64 + 255) / 256, 256, 0, stream>>>(rptr, csr_row_c, acc_e, sird, s_j,
                                                       dinv, b1, hbuf);

  // --- Layer 2 ---
  gemm2_kernel<<<(NN * 8 + 255) / 256, 256, 0, stream>>>(hbuf, W2, xh2);
  prop3_csr<<<(NN * 8 + 255) / 256, 256, 0, stream>>>(cptr, csr_col_r, xh2, Binv, acc_e2);
  prop4_csr<<<(NN * 8 + 255) / 256, 256, 0, stream>>>(rptr, csr_row_c, acc_e2, dinv, b2, out);
}